// Round 15
// baseline (2532.758 us; speedup 1.0000x reference)
//
#include <hip/hip_runtime.h>

#define SEQ  4096
#define HID  128
#define NBLK 64    // 64 blocks x 512 threads; block = 2 instances x 2 batch cols

typedef int   i32x4 __attribute__((ext_vector_type(4)));
typedef float f32x4 __attribute__((ext_vector_type(4)));

#define L2E  1.44269504088896340736f   // log2(e)
#define L2E2 2.88539008177792681472f   // 2*log2(e)

__device__ __forceinline__ float exp2_(float x) { return __builtin_amdgcn_exp2f(x); }
__device__ __forceinline__ float rcp_(float x)  { return __builtin_amdgcn_rcpf(x); }
__device__ __forceinline__ float sigm2(float xp) { return rcp_(1.f + exp2_(-xp)); }
__device__ __forceinline__ float tanh2(float xp) { return 1.f - 2.f * rcp_(1.f + exp2_(xp)); }

// Dual-instance phase-skewed LSTM. Instance A = waves 0-3 (cols 0,1),
// instance B = waves 4-7 (cols 2,3); HW puts wave w on SIMD w&3, so each SIMD
// hosts one A-wave + one B-wave. Each step = 2 barrier regions:
//   R_{2s}:   A does G(s)  [ds_read h, 16 MFMAs, selects -> v4 regs]
//             B does E(s-1)[activations, c/h update, h-write]   (VALU/TRANS)
//   R_{2s+1}: A does E(s), B does G(s)
// => every region each SIMD has one MFMA-issuing wave and one VALU-chain wave:
// the partner's 326cy MFMA issue hides the other's serial chain (r10's exposed
// ~530cy). Per-instance math identical to round 10 (i8 MFMA, f32 state).
__global__ __launch_bounds__(512, 2)
void lstm_mfma(const float* __restrict__ inputs,   // (B,S,3)
               const float* __restrict__ hx0,      // (B,128)
               const float* __restrict__ cx0,      // (B,128)
               const float* __restrict__ W_inp,    // (64,3)
               const float* __restrict__ b_inp,    // (64)
               const float* __restrict__ W_ih,     // (512,64)
               const float* __restrict__ b_ih,     // (512)
               const float* __restrict__ W_hh,     // (512,128)
               const float* __restrict__ b_hh,     // (512)
               const float* __restrict__ W_out,    // (40,128)
               const float* __restrict__ b_out,    // (40)
               float*       __restrict__ out)      // (B,40)
{
    // per-instance h state (int8), SINGLE-buffered (G-read and E-write are in
    // different barrier regions): byte (inst,kt,q,c,i) = h_q[kt*64+q*16+i][col c]
    __shared__ signed char xvT[2][2][4][2][16];   // 512 B
    // per-instance input ring: 2 phases x 8 slots x 2 cols x 4 floats
    __shared__ float uring[2][128];               // 1 KB
    __shared__ float hxf[4][HID + 4];             // final fp32 hx for out-proj

    const int tid  = threadIdx.x;
    const int w    = tid >> 6;        // wave 0..7
    const int lane = tid & 63;
    const int q    = lane >> 4;       // 0..3
    const int n    = lane & 15;
    const int inst = w >> 2;          // 0 = A, 1 = B
    const int wl   = w & 3;           // wave index within instance
    const int bbase = blockIdx.x * 4;
    const int cbase = bbase + inst * 2;

    const int  cc   = n & 1;                 // lane's batch column (within instance)
    const bool rb1  = (n >> 1) & 1;          // acc reg select bit 0
    const bool rb2  = (n >> 2) & 1;          // acc reg select bit 1
    const bool hi8  = (n >> 3) & 1;          // M-subtile select
    const int  rr   = (n >> 1) & 3;
    const int  hrow = wl * 16 + (hi8 ? 64 : 0) + q * 4 + rr;  // lane's hidden row

    // ---- A fragments: int8, per-row symmetric scale, 2 M-subtiles per gate ------
    // m = t*128 + (wl + 4s)*16 + n; A and B share the slot->k bijection (verified).
    i32x4 A[4][2][2];
    float dq[4];
    #pragma unroll
    for (int t = 0; t < 4; ++t) {
        #pragma unroll
        for (int s = 0; s < 2; ++s) {
            const int m = t * 128 + (wl + 4 * s) * 16 + n;
            const float* whr = W_hh + m * HID;
            float mx = 0.f;
            for (int k = 0; k < 128; ++k) mx = fmaxf(mx, fabsf(whr[k]));
            const float rs = (mx > 0.f) ? 127.f / mx : 0.f;
            #pragma unroll
            for (int kt = 0; kt < 2; ++kt) {
                union { signed char c[16]; i32x4 v; } pk;
                #pragma unroll
                for (int i = 0; i < 16; ++i)
                    pk.c[i] = (signed char)(int)rintf(whr[kt * 64 + q * 16 + i] * rs);
                A[t][s][kt] = pk.v;
            }
        }
        // dequant scale for THIS lane's epilogue row (recomputed deterministically)
        const int me = t * 128 + hrow;
        const float* whe = W_hh + me * HID;
        float mxe = 0.f;
        for (int k = 0; k < 128; ++k) mxe = fmaxf(mxe, fabsf(whe[k]));
        dq[t] = (mxe / 127.f) * (1.f / 127.f) * ((t == 2) ? L2E2 : L2E);
    }

    // ---- weff for THIS lane's epilogue row (exact f32 input proj, L2E-scaled) ---
    float4 wf[4];
    #pragma unroll
    for (int t = 0; t < 4; ++t) {
        const float scl = (t == 2) ? L2E2 : L2E;
        const int m2 = t * 128 + hrow;
        const float* wir = W_ih + m2 * 64;
        float wx = 0.f, wy = 0.f, wz = 0.f, bb = 0.f;
        for (int hh = 0; hh < 64; ++hh) {
            float wv = wir[hh];
            wx += wv * W_inp[hh * 3 + 0];
            wy += wv * W_inp[hh * 3 + 1];
            wz += wv * W_inp[hh * 3 + 2];
            bb += wv * b_inp[hh];
        }
        bb += b_ih[m2] + b_hh[m2];
        wf[t] = make_float4(wx * scl, wy * scl, wz * scl, bb * scl);
    }

    // ---- Loader lane mapping (wave 1 of each instance): 48 lanes = 8x2x3 --------
    const bool uldr = (wl == 1) && (lane < 48);
    const int  col0 = lane / 24, rem0 = lane % 24, slot0 = rem0 / 3, wi0 = rem0 % 3;
    const float* up0 = inputs + (size_t)(cbase + col0) * (SEQ * 3) + wi0;
    float* const urp = &uring[inst][0];

    // ---- Init LDS ----------------------------------------------------------------
    if (tid < 128) ((int*)xvT)[tid] = 0;
    __syncthreads();
    {   // h0 quantized: global col = tid>>7 (0..3), row = tid&127
        int gc = tid >> 7, h = tid & 127;
        float v = hx0[(bbase + gc) * HID + h];
        v = fminf(fmaxf(v, -1.f), 1.f);
        xvT[gc >> 1][h >> 6][(h >> 4) & 3][gc & 1][h & 15] =
            (signed char)(int)rintf(v * 127.f);
    }
    if (uldr) {   // phase0 slots = steps 0..7, phase1 = steps 8..15
        urp[slot0 * 8 + col0 * 4 + wi0]      = up0[slot0 * 3];
        urp[64 + slot0 * 8 + col0 * 4 + wi0] = up0[(8 + slot0) * 3];
    }
    float creg = cx0[(cbase + cc) * HID + hrow];
    __syncthreads();

    float pend0 = 0.f, hl = 0.f;
    int v40 = 0, v41 = 0, v42 = 0, v43 = 0;   // raw gate ints carried across regions
    int roff = 0;

    // ---- G phase: ds_read h, 16 MFMAs, lane-local selects -> v4? ----------------
#define G_PHASE(J)                                                                  \
    do {                                                                            \
        const i32x4 B0 = *reinterpret_cast<const i32x4*>(&xvT[inst][0][q][cc][0]);  \
        const i32x4 B1 = *reinterpret_cast<const i32x4*>(&xvT[inst][1][q][cc][0]);  \
        if (uldr) {                                                                 \
            if ((J) == 0) {                                                         \
                int st = sb + 8 + slot0; if (st > SEQ - 1) st = SEQ - 1;            \
                pend0 = up0[st * 3];                                                \
            } else if ((J) == 4) {                                                  \
                urp[(roff ^ 64) + slot0 * 8 + col0 * 4 + wi0] = pend0;              \
            }                                                                       \
        }                                                                           \
        const i32x4 z4 = {0, 0, 0, 0};                                              \
        __builtin_amdgcn_s_setprio(1);                                              \
        int vv[4];                                                                  \
        _Pragma("unroll")                                                           \
        for (int t = 0; t < 4; ++t) {                                               \
            i32x4 a0 = __builtin_amdgcn_mfma_i32_16x16x64_i8(A[t][0][0], B0, z4, 0, 0, 0); \
            a0       = __builtin_amdgcn_mfma_i32_16x16x64_i8(A[t][0][1], B1, a0, 0, 0, 0); \
            i32x4 a1 = __builtin_amdgcn_mfma_i32_16x16x64_i8(A[t][1][0], B0, z4, 0, 0, 0); \
            a1       = __builtin_amdgcn_mfma_i32_16x16x64_i8(A[t][1][1], B1, a1, 0, 0, 0); \
            int s0 = rb1 ? a0[1] : a0[0];                                           \
            int s1 = rb1 ? a0[3] : a0[2];                                           \
            int t0 = rb1 ? a1[1] : a1[0];                                           \
            int t1 = rb1 ? a1[3] : a1[2];                                           \
            vv[t] = hi8 ? (rb2 ? t1 : t0) : (rb2 ? s1 : s0);                        \
        }                                                                           \
        __builtin_amdgcn_s_setprio(0);                                              \
        v40 = vv[0]; v41 = vv[1]; v42 = vv[2]; v43 = vv[3];                         \
    } while (0)

    // ---- E phase: input proj + activations + c/h update + h-write ---------------
#define E_PHASE(UOFF)                                                               \
    do {                                                                            \
        const f32x4 u4 = *reinterpret_cast<const f32x4*>(urp + (UOFF) + cc * 4);    \
        float g0 = fmaf((float)v40, dq[0],                                          \
            fmaf(wf[0].x, u4[0], fmaf(wf[0].y, u4[1], fmaf(wf[0].z, u4[2], wf[0].w)))); \
        float g1 = fmaf((float)v41, dq[1],                                          \
            fmaf(wf[1].x, u4[0], fmaf(wf[1].y, u4[1], fmaf(wf[1].z, u4[2], wf[1].w)))); \
        float g2 = fmaf((float)v42, dq[2],                                          \
            fmaf(wf[2].x, u4[0], fmaf(wf[2].y, u4[1], fmaf(wf[2].z, u4[2], wf[2].w)))); \
        float g3 = fmaf((float)v43, dq[3],                                          \
            fmaf(wf[3].x, u4[0], fmaf(wf[3].y, u4[1], fmaf(wf[3].z, u4[2], wf[3].w)))); \
        float iv = sigm2(g0), fv = sigm2(g1);                                       \
        float gg = tanh2(g2), ov = sigm2(g3);                                       \
        creg = fv * creg + iv * gg;                                                 \
        float th = tanh2(creg * L2E2);                                              \
        float h  = ov * th;                                                         \
        hl = h;                                                                     \
        xvT[inst][hi8 ? 1 : 0][wl][cc][q * 4 + rr] =                                \
            (signed char)(int)rintf(h * 127.f);                                     \
    } while (0)

    // ---- Region loop: 2 barrier regions per step, instances phase-skewed --------
    for (int sb = 0; sb < SEQ; sb += 8) {
        #pragma unroll
        for (int j = 0; j < 8; ++j) {
            // EVEN region: A = G(sb+j), B = E(sb+j-1)
            if (inst == 0) {
                G_PHASE(j);
            } else {
                if (j > 0) { E_PHASE(roff + (j - 1) * 8); }
                else if (sb > 0) { E_PHASE((roff ^ 64) + 56); }
            }
            __syncthreads();
            // ODD region: A = E(sb+j), B = G(sb+j)
            if (inst == 0) {
                E_PHASE(roff + j * 8);
            } else {
                G_PHASE(j);
            }
            __syncthreads();
        }
        roff ^= 64;
    }
    // B's final epilogue: step SEQ-1 (phase flipped after the loop -> roff^64 +56)
    if (inst == 1) { E_PHASE((roff ^ 64) + 56); }

    // ---- Out projection: out[b] = W_out @ hx_last + b_out -----------------------
    hxf[inst * 2 + cc][hrow] = hl;
    __syncthreads();
    if (tid < 4 * 40) {
        int bl = tid / 40, o = tid % 40;
        const float* wr = W_out + o * HID;
        float a = b_out[o];
        #pragma unroll 8
        for (int k = 0; k < HID; ++k) a += wr[k] * hxf[bl][k];
        out[(bbase + bl) * 40 + o] = a;
    }
#undef G_PHASE
#undef E_PHASE
}

extern "C" void kernel_launch(void* const* d_in, const int* in_sizes, int n_in,
                              void* d_out, int out_size, void* d_ws, size_t ws_size,
                              hipStream_t stream) {
    const float* inputs = (const float*)d_in[0];
    const float* hx0    = (const float*)d_in[1];
    const float* cx0    = (const float*)d_in[2];
    const float* W_inp  = (const float*)d_in[3];
    const float* b_inp  = (const float*)d_in[4];
    const float* W_ih   = (const float*)d_in[5];
    const float* b_ih   = (const float*)d_in[6];
    const float* W_hh   = (const float*)d_in[7];
    const float* b_hh   = (const float*)d_in[8];
    const float* W_out  = (const float*)d_in[9];
    const float* b_out  = (const float*)d_in[10];
    float* out = (float*)d_out;

    lstm_mfma<<<NBLK, 512, 0, stream>>>(inputs, hx0, cx0, W_inp, b_inp, W_ih, b_ih,
                                        W_hh, b_hh, W_out, b_out, out);
}

// Round 16
// 1507.376 us; speedup vs baseline: 1.6802x; 1.6802x over previous
//
#include <hip/hip_runtime.h>

#define SEQ  4096
#define HID  128
#define BT   2            // real batch columns per block (replicated into 16 MFMA cols)
#define NBLK (256 / BT)   // 128 blocks, 256 threads each -> 1 wave per SIMD

typedef int   i32x4 __attribute__((ext_vector_type(4)));
typedef float f32x4 __attribute__((ext_vector_type(4)));

#define L2E  1.44269504088896340736f   // log2(e)
#define L2E2 2.88539008177792681472f   // 2*log2(e)

__device__ __forceinline__ float exp2_(float x) { return __builtin_amdgcn_exp2f(x); }
__device__ __forceinline__ float rcp_(float x)  { return __builtin_amdgcn_rcpf(x); }
// gate pre-scaled by log2e: sigmoid(x) = 1/(1+2^-x')
__device__ __forceinline__ float sigm2(float xp) { return rcp_(1.f + exp2_(-xp)); }
// gate pre-scaled by 2*log2e: tanh(x) = 1 - 2/(1+2^x')
__device__ __forceinline__ float tanh2(float xp) { return 1.f - 2.f * rcp_(1.f + exp2_(xp)); }

// One block = 2 batch columns, 4 waves (256 thr) -> ONE wave per SIMD.
// Round 16 = round 10 (best: 1461us) with ONE change: the in-loop
// __syncthreads() is replaced by {s_waitcnt lgkmcnt(0); s_barrier;
// sched_barrier(0)}. __syncthreads emits s_waitcnt vmcnt(0) before s_barrier
// (m97 finding), which drains the uldr wave's 8-step-ahead global input load
// at the FIRST barrier after issue -- the whole block then waits ~L2/L3
// latency once per 8 steps. The h-exchange only requires lgkmcnt(0) (LDS
// write visibility); the global load's vmcnt wait belongs at the j=4/12
// ring-write (wave-local, >=4 barriers of real slack), where the compiler
// places it via pend0's data dependency. Counted-vmcnt-across-barrier (T4).
__global__ __launch_bounds__(256, 2)
void lstm_mfma(const float* __restrict__ inputs,   // (B,S,3)
               const float* __restrict__ hx0,      // (B,128)
               const float* __restrict__ cx0,      // (B,128)
               const float* __restrict__ W_inp,    // (64,3)
               const float* __restrict__ b_inp,    // (64)
               const float* __restrict__ W_ih,     // (512,64)
               const float* __restrict__ b_ih,     // (512)
               const float* __restrict__ W_hh,     // (512,128)
               const float* __restrict__ b_hh,     // (512)
               const float* __restrict__ W_out,    // (40,128)
               const float* __restrict__ b_out,    // (40)
               float*       __restrict__ out)      // (B,40)
{
    // h state (int8), double-buffered, transposed:
    // byte (kt,q,c,i) = h_q[k = kt*64 + q*16 + i][col c]
    __shared__ signed char xvT[2][2][4][2][16];   // 512 B
    // input ring (f32): slot s&15 holds {u0,u1,u2,pad} per col, filled 8+ ahead
    __shared__ float uring[16][2][4];             // 512 B
    __shared__ float hxf[BT][HID + 4];            // final fp32 hx for out-projection

    const int tid  = threadIdx.x;
    const int w    = tid >> 6;        // wave 0..3 (one per SIMD)
    const int lane = tid & 63;
    const int q    = lane >> 4;       // 0..3
    const int n    = lane & 15;
    const int bbase = blockIdx.x * BT;

    const int  cc   = n & 1;                 // lane's batch column
    const bool rb1  = (n >> 1) & 1;          // acc reg select bit 0
    const bool rb2  = (n >> 2) & 1;          // acc reg select bit 1
    const bool hi8  = (n >> 3) & 1;          // M-subtile select
    const int  rr   = (n >> 1) & 3;
    const int  hrow = w * 16 + (hi8 ? 64 : 0) + q * 4 + rr;  // lane's hidden row

    // ---- A fragments: int8, per-row symmetric scale, 2 M-subtiles per gate ------
    // Lane (q,n), gate t, subtile s, K-tile kt holds W_hh[m][kt*64 + q*16 + i],
    // m = t*128 + (w + 4s)*16 + n. A and B share the slot->k bijection (verified).
    i32x4 A[4][2][2];
    float dq[4];                          // dequant scale for THIS lane's epilogue row
    #pragma unroll
    for (int t = 0; t < 4; ++t) {
        #pragma unroll
        for (int s = 0; s < 2; ++s) {
            const int m = t * 128 + (w + 4 * s) * 16 + n;
            const float* whr = W_hh + m * HID;
            float mx = 0.f;
            for (int k = 0; k < 128; ++k) mx = fmaxf(mx, fabsf(whr[k]));
            const float rs = (mx > 0.f) ? 127.f / mx : 0.f;
            #pragma unroll
            for (int kt = 0; kt < 2; ++kt) {
                union { signed char c[16]; i32x4 v; } pk;
                #pragma unroll
                for (int i = 0; i < 16; ++i)
                    pk.c[i] = (signed char)(int)rintf(whr[kt * 64 + q * 16 + i] * rs);
                A[t][s][kt] = pk.v;
            }
        }
        // epilogue row me = t*128 + hrow: recomputed identically by every lane
        // that touches row me (deterministic fp -> consistent with A-quant above)
        const int me = t * 128 + hrow;
        const float* whe = W_hh + me * HID;
        float mxe = 0.f;
        for (int k = 0; k < 128; ++k) mxe = fmaxf(mxe, fabsf(whe[k]));
        dq[t] = (mxe / 127.f) * (1.f / 127.f) * ((t == 2) ? L2E2 : L2E);
    }

    // ---- weff for THIS lane's epilogue row (input proj, exact f32, L2E-scaled) --
    float4 wf[4];
    #pragma unroll
    for (int t = 0; t < 4; ++t) {
        const float scl = (t == 2) ? L2E2 : L2E;
        const int m2 = t * 128 + hrow;
        const float* wir = W_ih + m2 * 64;
        float wx = 0.f, wy = 0.f, wz = 0.f, bb = 0.f;
        for (int hh = 0; hh < 64; ++hh) {
            float wv = wir[hh];
            wx += wv * W_inp[hh * 3 + 0];
            wy += wv * W_inp[hh * 3 + 1];
            wz += wv * W_inp[hh * 3 + 2];
            bb += wv * b_inp[hh];
        }
        bb += b_ih[m2] + b_hh[m2];
        wf[t] = make_float4(wx * scl, wy * scl, wz * scl, bb * scl);
    }

    // ---- Loader lane mapping (wave 1): 48 floats = 8 steps x 2 cols x 3 ---------
    const bool uldr = (w == 1) && (lane < 48);
    const int  col0 = lane / 24, rem0 = lane % 24, slot0 = rem0 / 3, wi0 = rem0 % 3;
    const float* up0 = inputs + (size_t)(bbase + col0) * (SEQ * 3) + wi0;

    // ---- Init LDS ----------------------------------------------------------------
    if (tid < 2 * 2 * 4 * 2 * 16 / 4) ((int*)xvT)[tid] = 0;
    __syncthreads();
    {   // h0 quantized (clip to [-1,1]: only perturbs step 1, damped by forget gate)
        int c = tid >> 7, h = tid & 127;
        float v = hx0[(bbase + c) * HID + h];
        v = fminf(fmaxf(v, -1.f), 1.f);
        xvT[0][h >> 6][(h >> 4) & 3][c][h & 15] = (signed char)(int)rintf(v * 127.f);
    }
    if (uldr) {   // ring slots 0..15 = steps 0..15
        uring[slot0][col0][wi0]     = up0[slot0 * 3];
        uring[8 + slot0][col0][wi0] = up0[(8 + slot0) * 3];
    }
    float creg = cx0[(bbase + cc) * HID + hrow];
    __syncthreads();

    float pend0 = 0.f, hl = 0.f;

    // ---- Recurrent loop: 16 statically-unrolled substeps per iteration -----------
    for (int sb = 0; sb < SEQ; sb += 16) {
        #pragma unroll
        for (int j = 0; j < 16; ++j) {
            signed char (*br)[4][2][16] = xvT[j & 1];
            signed char (*bw)[4][2][16] = xvT[(j + 1) & 1];

            // deep input prefetch: issue at j=0/8 (8+ steps ahead), write at j=4/12.
            // With the raw barrier below, this load now TRULY stays in flight
            // across barriers until pend0's use inserts the wave-local vmcnt wait.
            if (uldr) {
                if (j == 0) {
                    int st0 = sb + 8 + slot0; if (st0 > SEQ - 1) st0 = SEQ - 1;
                    pend0 = up0[st0 * 3];
                } else if (j == 4) {        // slots 8..15 <- steps sb+8..sb+15
                    uring[8 + slot0][col0][wi0] = pend0;
                } else if (j == 8) {
                    int st0 = sb + 16 + slot0; if (st0 > SEQ - 1) st0 = SEQ - 1;
                    pend0 = up0[st0 * 3];
                } else if (j == 12) {       // slots 0..7 <- steps sb+16..sb+23
                    uring[slot0][col0][wi0] = pend0;
                }
            }

            // u (f32x4 broadcast, static slot) + int8 B fragments (static offsets).
            // The inp FMAs below are independent of the B reads -> they execute in
            // the ds_read latency shadow (round 10's proven placement).
            const f32x4 u4 = *reinterpret_cast<const f32x4*>(&uring[j][cc][0]);
            const i32x4 B0 = *reinterpret_cast<const i32x4*>(&br[0][q][cc][0]);
            const i32x4 B1 = *reinterpret_cast<const i32x4*>(&br[1][q][cc][0]);

            // input projection (exact f32, independent of MFMA results)
            float inp[4];
            #pragma unroll
            for (int t = 0; t < 4; ++t)
                inp[t] = fmaf(wf[t].x, u4[0], fmaf(wf[t].y, u4[1],
                         fmaf(wf[t].z, u4[2], wf[t].w)));

            const i32x4 z4 = {0, 0, 0, 0};
            // per-gate: 4 MFMAs (2 subtiles x 2 K) then 1-of-8 select + activation;
            // activation VALU/TRANS hides under the next gate's MFMA drain.
            float gv4[4];
            #pragma unroll
            for (int t = 0; t < 4; ++t) {
                i32x4 a0 = __builtin_amdgcn_mfma_i32_16x16x64_i8(A[t][0][0], B0, z4, 0, 0, 0);
                a0       = __builtin_amdgcn_mfma_i32_16x16x64_i8(A[t][0][1], B1, a0, 0, 0, 0);
                i32x4 a1 = __builtin_amdgcn_mfma_i32_16x16x64_i8(A[t][1][0], B0, z4, 0, 0, 0);
                a1       = __builtin_amdgcn_mfma_i32_16x16x64_i8(A[t][1][1], B1, a1, 0, 0, 0);
                int s0 = rb1 ? a0[1] : a0[0];
                int s1 = rb1 ? a0[3] : a0[2];
                int v0 = rb2 ? s1 : s0;
                int t0 = rb1 ? a1[1] : a1[0];
                int t1 = rb1 ? a1[3] : a1[2];
                int v1 = rb2 ? t1 : t0;
                int v  = hi8 ? v1 : v0;
                gv4[t] = (float)v * dq[t] + inp[t];
            }

            // one LSTM update per lane (fp32 state); all exp are exp2
            float iv = sigm2(gv4[0]), fv = sigm2(gv4[1]);
            float gg = tanh2(gv4[2]), ov = sigm2(gv4[3]);
            creg = fv * creg + iv * gg;
            float th = tanh2(creg * L2E2);
            float h  = ov * th;                       // |h| < 1 by construction
            hl = h;

            bw[hi8 ? 1 : 0][w][cc][q * 4 + rr] = (signed char)(int)rintf(h * 127.f);

            // Raw barrier: drain LDS ops only (h-write visibility), leave the
            // global prefetch in flight (vs __syncthreads' vmcnt(0) drain).
            // sched_barrier(0) fences compiler reordering of the following
            // step's ds_reads above the barrier (rule #18).
            asm volatile("s_waitcnt lgkmcnt(0)" ::: "memory");
            __builtin_amdgcn_s_barrier();
            __builtin_amdgcn_sched_barrier(0);
        }
    }

    // ---- Out projection: out[b] = W_out @ hx_last + b_out (f32 h, unquantized) ---
    hxf[cc][hrow] = hl;
    __syncthreads();
    if (tid < BT * 40) {
        int bl = tid / 40, o = tid % 40;
        const float* wr = W_out + o * HID;
        float a = b_out[o];
        #pragma unroll 8
        for (int k = 0; k < HID; ++k) a += wr[k] * hxf[bl][k];
        out[(bbase + bl) * 40 + o] = a;
    }
}

extern "C" void kernel_launch(void* const* d_in, const int* in_sizes, int n_in,
                              void* d_out, int out_size, void* d_ws, size_t ws_size,
                              hipStream_t stream) {
    const float* inputs = (const float*)d_in[0];
    const float* hx0    = (const float*)d_in[1];
    const float* cx0    = (const float*)d_in[2];
    const float* W_inp  = (const float*)d_in[3];
    const float* b_inp  = (const float*)d_in[4];
    const float* W_ih   = (const float*)d_in[5];
    const float* b_ih   = (const float*)d_in[6];
    const float* W_hh   = (const float*)d_in[7];
    const float* b_hh   = (const float*)d_in[8];
    const float* W_out  = (const float*)d_in[9];
    const float* b_out  = (const float*)d_in[10];
    float* out = (float*)d_out;

    lstm_mfma<<<NBLK, 256, 0, stream>>>(inputs, hx0, cx0, W_inp, b_inp, W_ih, b_ih,
                                        W_hh, b_hh, W_out, b_out, out);
}

// Round 17
// 1467.326 us; speedup vs baseline: 1.7261x; 1.0273x over previous
//
#include <hip/hip_runtime.h>

#define SEQ  4096
#define HID  128
#define BT   2            // real batch columns per block (replicated into 16 MFMA cols)
#define NBLK (256 / BT)   // 128 blocks, 256 threads each -> 1 wave per SIMD

typedef int   i32x4 __attribute__((ext_vector_type(4)));
typedef float f32x4 __attribute__((ext_vector_type(4)));

#define L2E  1.44269504088896340736f   // log2(e)
#define L2E2 2.88539008177792681472f   // 2*log2(e)

__device__ __forceinline__ float exp2_(float x) { return __builtin_amdgcn_exp2f(x); }
__device__ __forceinline__ float rcp_(float x)  { return __builtin_amdgcn_rcpf(x); }
// gate pre-scaled by log2e: sigmoid(x) = 1/(1+2^-x')
__device__ __forceinline__ float sigm2(float xp) { return rcp_(1.f + exp2_(-xp)); }
// gate pre-scaled by 2*log2e: tanh(x) = 1 - 2/(1+2^x')
__device__ __forceinline__ float tanh2(float xp) { return 1.f - 2.f * rcp_(1.f + exp2_(xp)); }

// FINAL KERNEL == round 10 (session best: 1461us, 17.7x over round-1 baseline).
// One block = 2 batch columns, 4 waves (256 thr) -> ONE wave per SIMD.
// Design ledger (what's proven, rounds in parens):
//  - i8 MFMA recurrent GEMM, K=64 (halves MFMA issue vs f16; exact int math,
//    per-row W scales + fixed 1/127 h scale; absmax 1.95e-3, 3.5x margin) (r9)
//  - 4 waves, lane-local epilogue: each lane does exactly ONE LSTM update;
//    extra same-phase waves only add pipe contention (r4->r10, r6, r15)
//  - 16-step static unroll: all LDS addresses base+immediate (r8)
//  - input projection in the ds_read latency shadow (r10 vs r11/r12)
//  - __launch_bounds__(256,2): the 128-VGPR schedule beats uncapped despite a
//    ~14B/step hidden scratch spill; parking state in LDS costs more (r11-r14)
//  - plain __syncthreads(): the vmcnt(0) drain is free, inputs are L2-hot (r16)
//  - deep input ring (8+ steps ahead), f32, wave-1 loader lanes (r4,r8)
// Residual ~330cy/step is the irreducible serial chain (barrier skew ->
// ds_read -> MFMA dep/issue -> TRANS chain -> quantize -> ds_write) x4096.
__global__ __launch_bounds__(256, 2)
void lstm_mfma(const float* __restrict__ inputs,   // (B,S,3)
               const float* __restrict__ hx0,      // (B,128)
               const float* __restrict__ cx0,      // (B,128)
               const float* __restrict__ W_inp,    // (64,3)
               const float* __restrict__ b_inp,    // (64)
               const float* __restrict__ W_ih,     // (512,64)
               const float* __restrict__ b_ih,     // (512)
               const float* __restrict__ W_hh,     // (512,128)
               const float* __restrict__ b_hh,     // (512)
               const float* __restrict__ W_out,    // (40,128)
               const float* __restrict__ b_out,    // (40)
               float*       __restrict__ out)      // (B,40)
{
    // h state (int8), double-buffered, transposed:
    // byte (kt,q,c,i) = h_q[k = kt*64 + q*16 + i][col c]
    __shared__ signed char xvT[2][2][4][2][16];   // 512 B
    // input ring (f32): slot s&15 holds {u0,u1,u2,pad} per col, filled 8+ ahead
    __shared__ float uring[16][2][4];             // 512 B
    __shared__ float hxf[BT][HID + 4];            // final fp32 hx for out-projection

    const int tid  = threadIdx.x;
    const int w    = tid >> 6;        // wave 0..3 (one per SIMD)
    const int lane = tid & 63;
    const int q    = lane >> 4;       // 0..3
    const int n    = lane & 15;
    const int bbase = blockIdx.x * BT;

    const int  cc   = n & 1;                 // lane's batch column
    const bool rb1  = (n >> 1) & 1;          // acc reg select bit 0
    const bool rb2  = (n >> 2) & 1;          // acc reg select bit 1
    const bool hi8  = (n >> 3) & 1;          // M-subtile select
    const int  rr   = (n >> 1) & 3;
    const int  hrow = w * 16 + (hi8 ? 64 : 0) + q * 4 + rr;  // lane's hidden row

    // ---- A fragments: int8, per-row symmetric scale, 2 M-subtiles per gate ------
    // Lane (q,n), gate t, subtile s, K-tile kt holds W_hh[m][kt*64 + q*16 + i],
    // m = t*128 + (w + 4s)*16 + n. A and B share the slot->k bijection (verified).
    i32x4 A[4][2][2];
    float dq[4];                          // dequant scale for THIS lane's epilogue row
    #pragma unroll
    for (int t = 0; t < 4; ++t) {
        #pragma unroll
        for (int s = 0; s < 2; ++s) {
            const int m = t * 128 + (w + 4 * s) * 16 + n;
            const float* whr = W_hh + m * HID;
            float mx = 0.f;
            for (int k = 0; k < 128; ++k) mx = fmaxf(mx, fabsf(whr[k]));
            const float rs = (mx > 0.f) ? 127.f / mx : 0.f;
            #pragma unroll
            for (int kt = 0; kt < 2; ++kt) {
                union { signed char c[16]; i32x4 v; } pk;
                #pragma unroll
                for (int i = 0; i < 16; ++i)
                    pk.c[i] = (signed char)(int)rintf(whr[kt * 64 + q * 16 + i] * rs);
                A[t][s][kt] = pk.v;
            }
        }
        // epilogue row me = t*128 + hrow: recomputed identically by every lane
        // that touches row me (deterministic fp -> consistent with A-quant above)
        const int me = t * 128 + hrow;
        const float* whe = W_hh + me * HID;
        float mxe = 0.f;
        for (int k = 0; k < 128; ++k) mxe = fmaxf(mxe, fabsf(whe[k]));
        dq[t] = (mxe / 127.f) * (1.f / 127.f) * ((t == 2) ? L2E2 : L2E);
    }

    // ---- weff for THIS lane's epilogue row (input proj, exact f32, L2E-scaled) --
    float4 wf[4];
    #pragma unroll
    for (int t = 0; t < 4; ++t) {
        const float scl = (t == 2) ? L2E2 : L2E;
        const int m2 = t * 128 + hrow;
        const float* wir = W_ih + m2 * 64;
        float wx = 0.f, wy = 0.f, wz = 0.f, bb = 0.f;
        for (int hh = 0; hh < 64; ++hh) {
            float wv = wir[hh];
            wx += wv * W_inp[hh * 3 + 0];
            wy += wv * W_inp[hh * 3 + 1];
            wz += wv * W_inp[hh * 3 + 2];
            bb += wv * b_inp[hh];
        }
        bb += b_ih[m2] + b_hh[m2];
        wf[t] = make_float4(wx * scl, wy * scl, wz * scl, bb * scl);
    }

    // ---- Loader lane mapping (wave 1): 48 floats = 8 steps x 2 cols x 3 ---------
    const bool uldr = (w == 1) && (lane < 48);
    const int  col0 = lane / 24, rem0 = lane % 24, slot0 = rem0 / 3, wi0 = rem0 % 3;
    const float* up0 = inputs + (size_t)(bbase + col0) * (SEQ * 3) + wi0;

    // ---- Init LDS ----------------------------------------------------------------
    if (tid < 2 * 2 * 4 * 2 * 16 / 4) ((int*)xvT)[tid] = 0;
    __syncthreads();
    {   // h0 quantized (clip to [-1,1]: only perturbs step 1, damped by forget gate)
        int c = tid >> 7, h = tid & 127;
        float v = hx0[(bbase + c) * HID + h];
        v = fminf(fmaxf(v, -1.f), 1.f);
        xvT[0][h >> 6][(h >> 4) & 3][c][h & 15] = (signed char)(int)rintf(v * 127.f);
    }
    if (uldr) {   // ring slots 0..15 = steps 0..15
        uring[slot0][col0][wi0]     = up0[slot0 * 3];
        uring[8 + slot0][col0][wi0] = up0[(8 + slot0) * 3];
    }
    float creg = cx0[(bbase + cc) * HID + hrow];
    __syncthreads();

    float pend0 = 0.f, hl = 0.f;

    // ---- Recurrent loop: 16 statically-unrolled substeps per iteration -----------
    for (int sb = 0; sb < SEQ; sb += 16) {
        #pragma unroll
        for (int j = 0; j < 16; ++j) {
            signed char (*br)[4][2][16] = xvT[j & 1];
            signed char (*bw)[4][2][16] = xvT[(j + 1) & 1];

            // deep input prefetch: issue at j=0/8 (8+ steps ahead), write at j=4/12
            if (uldr) {
                if (j == 0) {
                    int st0 = sb + 8 + slot0; if (st0 > SEQ - 1) st0 = SEQ - 1;
                    pend0 = up0[st0 * 3];
                } else if (j == 4) {        // slots 8..15 <- steps sb+8..sb+15
                    uring[8 + slot0][col0][wi0] = pend0;
                } else if (j == 8) {
                    int st0 = sb + 16 + slot0; if (st0 > SEQ - 1) st0 = SEQ - 1;
                    pend0 = up0[st0 * 3];
                } else if (j == 12) {       // slots 0..7 <- steps sb+16..sb+23
                    uring[slot0][col0][wi0] = pend0;
                }
            }

            // u (f32x4 broadcast, static slot) + int8 B fragments (static offsets).
            // The inp FMAs below are independent of the B reads -> they execute in
            // the ds_read latency shadow.
            const f32x4 u4 = *reinterpret_cast<const f32x4*>(&uring[j][cc][0]);
            const i32x4 B0 = *reinterpret_cast<const i32x4*>(&br[0][q][cc][0]);
            const i32x4 B1 = *reinterpret_cast<const i32x4*>(&br[1][q][cc][0]);

            // input projection (exact f32, independent of MFMA results)
            float inp[4];
            #pragma unroll
            for (int t = 0; t < 4; ++t)
                inp[t] = fmaf(wf[t].x, u4[0], fmaf(wf[t].y, u4[1],
                         fmaf(wf[t].z, u4[2], wf[t].w)));

            const i32x4 z4 = {0, 0, 0, 0};
            // per-gate: 4 MFMAs (2 subtiles x 2 K) then 1-of-8 select + activation;
            // activation VALU/TRANS hides under the next gate's MFMA drain.
            float gv4[4];
            #pragma unroll
            for (int t = 0; t < 4; ++t) {
                i32x4 a0 = __builtin_amdgcn_mfma_i32_16x16x64_i8(A[t][0][0], B0, z4, 0, 0, 0);
                a0       = __builtin_amdgcn_mfma_i32_16x16x64_i8(A[t][0][1], B1, a0, 0, 0, 0);
                i32x4 a1 = __builtin_amdgcn_mfma_i32_16x16x64_i8(A[t][1][0], B0, z4, 0, 0, 0);
                a1       = __builtin_amdgcn_mfma_i32_16x16x64_i8(A[t][1][1], B1, a1, 0, 0, 0);
                int s0 = rb1 ? a0[1] : a0[0];
                int s1 = rb1 ? a0[3] : a0[2];
                int v0 = rb2 ? s1 : s0;
                int t0 = rb1 ? a1[1] : a1[0];
                int t1 = rb1 ? a1[3] : a1[2];
                int v1 = rb2 ? t1 : t0;
                int v  = hi8 ? v1 : v0;
                gv4[t] = (float)v * dq[t] + inp[t];
            }

            // one LSTM update per lane (fp32 state); all exp are exp2
            float iv = sigm2(gv4[0]), fv = sigm2(gv4[1]);
            float gg = tanh2(gv4[2]), ov = sigm2(gv4[3]);
            creg = fv * creg + iv * gg;
            float th = tanh2(creg * L2E2);
            float h  = ov * th;                       // |h| < 1 by construction
            hl = h;

            bw[hi8 ? 1 : 0][w][cc][q * 4 + rr] = (signed char)(int)rintf(h * 127.f);
            __syncthreads();
        }
    }

    // ---- Out projection: out[b] = W_out @ hx_last + b_out (f32 h, unquantized) ---
    hxf[cc][hrow] = hl;
    __syncthreads();
    if (tid < BT * 40) {
        int bl = tid / 40, o = tid % 40;
        const float* wr = W_out + o * HID;
        float a = b_out[o];
        #pragma unroll 8
        for (int k = 0; k < HID; ++k) a += wr[k] * hxf[bl][k];
        out[(bbase + bl) * 40 + o] = a;
    }
}

extern "C" void kernel_launch(void* const* d_in, const int* in_sizes, int n_in,
                              void* d_out, int out_size, void* d_ws, size_t ws_size,
                              hipStream_t stream) {
    const float* inputs = (const float*)d_in[0];
    const float* hx0    = (const float*)d_in[1];
    const float* cx0    = (const float*)d_in[2];
    const float* W_inp  = (const float*)d_in[3];
    const float* b_inp  = (const float*)d_in[4];
    const float* W_ih   = (const float*)d_in[5];
    const float* b_ih   = (const float*)d_in[6];
    const float* W_hh   = (const float*)d_in[7];
    const float* b_hh   = (const float*)d_in[8];
    const float* W_out  = (const float*)d_in[9];
    const float* b_out  = (const float*)d_in[10];
    float* out = (float*)d_out;

    lstm_mfma<<<NBLK, 256, 0, stream>>>(inputs, hx0, cx0, W_inp, b_inp, W_ih, b_ih,
                                        W_hh, b_hh, W_out, b_out, out);
}